// Round 2
// baseline (4509.100 us; speedup 1.0000x reference)
//
#include <hip/hip_runtime.h>
#include <hip/hip_bf16.h>

// Elman RNN: B=256, T=512, H=1024, O=256 (fp32 in/out), MI355X gfx950.
// Round 9: direct-to-register B-fragment polling (revert of r8's XCD gamble).
// r8 post-mortem: no architected "XCD scope" exists in the sc bits; cached
// polls also tag-alias at 4-step staleness. Back to r7's proven sc0|sc1
// fabric exchange. New in r9: the main loop no longer stages h through LDS.
// Each wave loads its MFMA B-fragments DIRECTLY into registers
// (lane (q,n), frag ks <- 16B at h[(row0+n)*H + kq*256 + ks*32 + q*8]),
// tag-checks all 32 dwords, retries on staleness. This deletes the LDS
// staging writes, the lgkmcnt wait, the pairflag partner spin, and all
// main-loop LDS bank conflicts (1.68e7/dispatch in r7). htile staging kept
// only for the one-time epilogue. Everything else identical to r7.

#define Bsz 256
#define Tn  512
#define Hn  1024
#define On  256

typedef __attribute__((ext_vector_type(8))) _Float16 f16x8;  // 4 VGPR
typedef __attribute__((ext_vector_type(4))) float f32x4;
typedef __attribute__((ext_vector_type(4))) int   i32x4;
typedef __attribute__((ext_vector_type(2))) int   i32x2;

__device__ __forceinline__ unsigned f2h(float f) {
    _Float16 h = (_Float16)f;
    union { _Float16 h; unsigned short s; } u; u.h = h;
    return (unsigned)u.s;
}

__device__ __forceinline__ f16x8 as_f16x8(i32x4 v) {
    union { i32x4 i; f16x8 h; } u; u.i = v; return u.h;
}

// tanh = (e^{2x}-1)/(e^{2x}+1); |err| ~1e-6 << fp16 rounding.
__device__ __forceinline__ float fast_tanh(float x) {
    float xc = fminf(fmaxf(x, -9.f), 9.f);
    float e  = __builtin_amdgcn_exp2f(xc * 2.8853900817779268f);
    return (e - 1.f) * __builtin_amdgcn_rcpf(e + 1.f);
}

#define MFMA_F16 __builtin_amdgcn_mfma_f32_16x16x32_f16

// Epilogue-only: poll-stage region kq (cols kq*256..+255), rows r0..r0+7 of
// this group's h slice into swizzled LDS. sc0|sc1 = fabric-coherent (proven).
__device__ __forceinline__ void stage_quarter(const short* __restrict__ hsrc,
                                              short* __restrict__ htile,
                                              int row0, int cg, int kq,
                                              int lane, unsigned tag) {
    const int half = lane >> 5, gl = lane & 31, r0 = cg * 8;
    const short* a0 = hsrc + (size_t)(row0 + r0 + 0 + half) * Hn + kq * 256 + gl * 8;
    const short* a1 = hsrc + (size_t)(row0 + r0 + 2 + half) * Hn + kq * 256 + gl * 8;
    const short* a2 = hsrc + (size_t)(row0 + r0 + 4 + half) * Hn + kq * 256 + gl * 8;
    const short* a3 = hsrc + (size_t)(row0 + r0 + 6 + half) * Hn + kq * 256 + gl * 8;
    i32x4 t0, t1, t2, t3;
    int spin = 0;
    for (;;) {
        asm volatile("global_load_dwordx4 %0, %1, off sc0 sc1"
                     : "=&v"(t0) : "v"(a0) : "memory");
        asm volatile("global_load_dwordx4 %0, %1, off sc0 sc1"
                     : "=&v"(t1) : "v"(a1) : "memory");
        asm volatile("global_load_dwordx4 %0, %1, off sc0 sc1"
                     : "=&v"(t2) : "v"(a2) : "memory");
        asm volatile("global_load_dwordx4 %0, %1, off sc0 sc1"
                     : "=&v"(t3) : "v"(a3) : "memory");
        asm volatile("s_waitcnt vmcnt(0)" ::: "memory");
        unsigned bad = 0;
#pragma unroll
        for (int e = 0; e < 4; ++e)
            bad |= (unsigned)(t0[e] ^ tag) | (unsigned)(t1[e] ^ tag) |
                   (unsigned)(t2[e] ^ tag) | (unsigned)(t3[e] ^ tag);
        if (!__any(bad & 1u)) break;
        if (++spin > (1 << 20)) break;   // hang insurance only
    }
    i32x4 tv[4] = {t0, t1, t2, t3};
#pragma unroll
    for (int p = 0; p < 4; ++p) {
        int row = r0 + 2 * p + half;
        int g   = kq * 32 + gl;
        int idx = row * 128 + (g ^ (row & 7));
        *(i32x4*)(htile + idx * 8) = tv[p];
    }
}

__global__ __launch_bounds__(512, 2) void rnn_kernel(
    const float* __restrict__ x,      // [B][T]
    const float* __restrict__ W_ih,   // [1+H][H]
    const float* __restrict__ b_ih,   // [H]
    const float* __restrict__ W_ho,   // [H][O]
    const float* __restrict__ b_ho,   // [O]
    float* __restrict__ out,          // [B][O]
    short* __restrict__ hbuf)         // ws: 2 * B * H fp16
{
    const int tid  = threadIdx.x;
    const int lane = tid & 63;
    const int w    = tid >> 6;      // wave 0..7
    const int cg   = w >> 2;        // col-group 0..1 (64 cols each)
    const int kq   = w & 3;         // k-quarter 0..3; owns m-tile kq of its cg
    const int q    = lane >> 4;
    const int n    = lane & 15;     // batch row (B/D col)

    const int i = blockIdx.x & 15;  // batch group
    const int j = blockIdx.x >> 4;  // member 0..7
    const int colbase = j * 128 + cg * 64;
    const int owncol  = colbase + kq * 16 + 4 * q;  // owner lane's 4 h cols
    const int row0    = i * 16;

    __shared__ float x_lds[16][Tn + 1];     // 32.8 KB
    __shared__ short htile[16 * Hn];        // 32 KB swizzled fp16 (epilogue)
    __shared__ float redbuf[2][8 * 3 * 256];// 48 KB b128 partial exchange

    // Stage x rows (coalesced fp32).
    for (int idx = tid; idx < 16 * Tn; idx += 512) {
        int r = idx >> 9, tt = idx & (Tn - 1);
        x_lds[r][tt] = x[(row0 + r) * Tn + tt];
    }

    // A = W^T frags (fp16): wave (cg,kq), tile mt: lane (q,n) holds
    // A[m=n][k=kq*256+ks*32+q*8+e] = W_ih[1+k][colbase+mt*16+n].
    f16x8 wfrag[32];
#pragma unroll
    for (int mt = 0; mt < 4; ++mt)
#pragma unroll
        for (int ks = 0; ks < 8; ++ks) {
#pragma unroll
            for (int e = 0; e < 8; ++e) {
                int k = kq * 256 + ks * 32 + q * 8 + e;
                wfrag[mt * 8 + ks][e] =
                    (_Float16)W_ih[(size_t)(1 + k) * Hn + colbase + mt * 16 + n];
            }
        }
    const float4 bias4 = *(const float4*)(b_ih + owncol);
    const float4 w04   = *(const float4*)(W_ih + owncol);  // row 0 (x weight)

    __syncthreads();

    short* h0 = hbuf;
    short* h1 = hbuf + Bsz * Hn;
    const int swn   = n & 7;
    const int slot16 = (q * 16 + n) * 4;  // lane's 16B slot in a redbuf plane
    const f32x4 zero4 = {0.f, 0.f, 0.f, 0.f};

    // Per-lane B-fragment base: row (row0+n), cols kq*256 + q*8 (+ ks*32).
    const size_t brow = (size_t)(row0 + n) * Hn + kq * 256 + q * 8;

    for (int t = 0; t < Tn; ++t) {
        const float xv = x_lds[n][t];
        f32x4 aown = {bias4.x + xv * w04.x, bias4.y + xv * w04.y,
                      bias4.z + xv * w04.z, bias4.w + xv * w04.w};
        f32x4 hv;

        if (t > 0) {
            // ---- Direct-to-register B poll (no LDS, no pairflag) ----
            const short* bb = ((t & 1) ? h1 : h0) + brow;
            const unsigned tag = (unsigned)((t + 1) >> 1) & 1u;
            i32x4 bf[8];
            int spin = 0;
            for (;;) {
#pragma unroll
                for (int ks = 0; ks < 8; ++ks)
                    asm volatile("global_load_dwordx4 %0, %1, off sc0 sc1"
                                 : "=&v"(bf[ks]) : "v"(bb + ks * 32) : "memory");
                asm volatile("s_waitcnt vmcnt(0)" ::: "memory");
                unsigned bad = 0;
#pragma unroll
                for (int ks = 0; ks < 8; ++ks)
#pragma unroll
                    for (int e = 0; e < 4; ++e)
                        bad |= (unsigned)bf[ks][e] ^ tag;
                if (!__any(bad & 1u)) break;
                if (++spin > (1 << 20)) break;   // hang insurance only
            }

            f32x4 acc0 = (kq == 0) ? aown : zero4;
            f32x4 acc1 = (kq == 1) ? aown : zero4;
            f32x4 acc2 = (kq == 2) ? aown : zero4;
            f32x4 acc3 = (kq == 3) ? aown : zero4;
#pragma unroll
            for (int ks = 0; ks < 8; ++ks) {
                f16x8 b = as_f16x8(bf[ks]);
                acc0 = MFMA_F16(wfrag[0 * 8 + ks], b, acc0, 0, 0, 0);
                acc1 = MFMA_F16(wfrag[1 * 8 + ks], b, acc1, 0, 0, 0);
                acc2 = MFMA_F16(wfrag[2 * 8 + ks], b, acc2, 0, 0, 0);
                acc3 = MFMA_F16(wfrag[3 * 8 + ks], b, acc3, 0, 0, 0);
            }

            // Exchange k-partials, b128 conflict-free, double-buffered.
            float* rb = redbuf[t & 1];
#define WRITE_PART(MT, ACC)                                                  \
            if (kq != MT) {                                                  \
                int src = (kq < MT) ? kq : kq - 1;                           \
                *(f32x4*)(rb + ((cg * 4 + MT) * 3 + src) * 256 + slot16) = ACC;\
            }
            WRITE_PART(0, acc0)
            WRITE_PART(1, acc1)
            WRITE_PART(2, acc2)
            WRITE_PART(3, acc3)
#undef WRITE_PART
            __syncthreads();

            hv = (kq == 0) ? acc0 : (kq == 1) ? acc1 : (kq == 2) ? acc2 : acc3;
            const float* bp = rb + (cg * 4 + kq) * 3 * 256 + slot16;
            f32x4 p0 = *(const f32x4*)(bp);
            f32x4 p1 = *(const f32x4*)(bp + 256);
            f32x4 p2 = *(const f32x4*)(bp + 512);
            hv = hv + p0 + p1 + p2;
        } else {
            hv = aown;
        }

        // Store h_{t+1}: buffer (t+1)&1, tag(t+1)=((t+2)>>1)&1 in bit 0 of
        // every dword. Fire-and-forget write-through (r7-proven visibility).
        unsigned tagn = (unsigned)((t + 2) >> 1) & 1u;
        unsigned e0 = f2h(fast_tanh(hv[0])), e1 = f2h(fast_tanh(hv[1]));
        unsigned e2 = f2h(fast_tanh(hv[2])), e3 = f2h(fast_tanh(hv[3]));
        i32x2 pk;
        pk[0] = (int)(((e0 & ~1u) | tagn) | (e1 << 16));
        pk[1] = (int)(((e2 & ~1u) | tagn) | (e3 << 16));
        short* hdst = (((t + 1) & 1) ? h1 : h0) + (size_t)(row0 + n) * Hn + owncol;
        asm volatile("global_store_dwordx2 %0, %1, off sc0 sc1"
                     :: "v"(hdst), "v"(pk) : "memory");
    }

    // ---- Epilogue: out[16i..+16][32j..+32] = h_T @ W_ho + b_ho ----
    // h_512 in buffer 0, tag 0. All quarters staged, then full barrier.
    stage_quarter(h0, htile, row0, cg, kq, lane, 0u);
    __syncthreads();

    f32x4 e0 = zero4, e1 = zero4;        // nt = 0,1 (16 out-cols each)
    {
        const i32x4* lrow = (const i32x4*)(htile + n * Hn);
#pragma unroll
        for (int kk = 0; kk < 4; ++kk) {
            f16x8 af = as_f16x8(lrow[(w * 16 + kk * 4 + q) ^ swn]);
            f16x8 b0, b1;
#pragma unroll
            for (int e = 0; e < 8; ++e) {
                const float* wp = W_ho +
                    (size_t)(w * 128 + kk * 32 + q * 8 + e) * On + j * 32 + n;
                b0[e] = (_Float16)wp[0];
                b1[e] = (_Float16)wp[16];
            }
            e0 = MFMA_F16(af, b0, e0, 0, 0, 0);
            e1 = MFMA_F16(af, b1, e1, 0, 0, 0);
        }
    }
    {   // scratch in redbuf[0]: [w][16 rows][33]: D[m=4q+r][col=nt*16+n].
        float* re = redbuf[0] + w * 528;
#pragma unroll
        for (int r = 0; r < 4; ++r) {
            re[(4 * q + r) * 33 + n]      = e0[r];
            re[(4 * q + r) * 33 + 16 + n] = e1[r];
        }
    }
    __syncthreads();
    {
        int r = tid >> 5, c = tid & 31;
        float s = b_ho[j * 32 + c];
#pragma unroll
        for (int w8 = 0; w8 < 8; ++w8)
            s += redbuf[0][w8 * 528 + r * 33 + c];
        out[(size_t)(row0 + r) * On + j * 32 + c] = s;
    }
}

extern "C" void kernel_launch(void* const* d_in, const int* in_sizes, int n_in,
                              void* d_out, int out_size, void* d_ws, size_t ws_size,
                              hipStream_t stream) {
    const float* x    = (const float*)d_in[0];
    const float* W_ih = (const float*)d_in[1];
    const float* b_ih = (const float*)d_in[2];
    const float* W_ho = (const float*)d_in[3];
    const float* b_ho = (const float*)d_in[4];
    float* out = (float*)d_out;

    size_t need = (size_t)2 * Bsz * Hn * sizeof(short);
    if (ws_size < need) return;

    short* hbuf = (short*)d_ws;

    rnn_kernel<<<128, 512, 0, stream>>>(x, W_ih, b_ih, W_ho, b_ho, out, hbuf);
}

// Round 3
// 1438.184 us; speedup vs baseline: 3.1353x; 3.1353x over previous
//
#include <hip/hip_runtime.h>
#include <hip/hip_bf16.h>

// Elman RNN: B=256, T=512, H=1024, O=256 (fp32 in/out), MI355X gfx950.
// Round 10: flag-gated polling on top of the r7 structure.
// r9 post-mortem: direct-to-reg polling doubled + de-coalesced poll traffic
// and ran 4.2x slower -> the exchange is CONGESTION-limited (128 WGs
// re-reading 4KB/wave/round saturate L3/fabric and inflate the RT they
// wait on). r10 keeps r7's data path verbatim (coalesced stage-to-LDS,
// pairflag partner sync, redbuf k-exchange, tag-in-data validation) but
// gates each data poll behind a 64B flag spin: producer waves fire-and-
// forget a per-wave flag (t+1) after their tagged h-store (no ack wait;
// tags remain the correctness mechanism). Consumers spin on one cache
// line of flags (+ s_sleep backoff), then run the tagged data poll once.
// Poll bandwidth drops ~60x. Flags are monotonic (no aliasing), zeroed
// per launch by stream-ordered memset.

#define Bsz 256
#define Tn  512
#define Hn  1024
#define On  256

typedef __attribute__((ext_vector_type(8))) _Float16 f16x8;  // 4 VGPR
typedef __attribute__((ext_vector_type(4))) float f32x4;
typedef __attribute__((ext_vector_type(4))) int   i32x4;
typedef __attribute__((ext_vector_type(2))) int   i32x2;

__device__ __forceinline__ unsigned f2h(float f) {
    _Float16 h = (_Float16)f;
    union { _Float16 h; unsigned short s; } u; u.h = h;
    return (unsigned)u.s;
}

__device__ __forceinline__ f16x8 as_f16x8(i32x4 v) {
    union { i32x4 i; f16x8 h; } u; u.i = v; return u.h;
}

// tanh = (e^{2x}-1)/(e^{2x}+1); |err| ~1e-6 << fp16 rounding.
__device__ __forceinline__ float fast_tanh(float x) {
    float xc = fminf(fmaxf(x, -9.f), 9.f);
    float e  = __builtin_amdgcn_exp2f(xc * 2.8853900817779268f);
    return (e - 1.f) * __builtin_amdgcn_rcpf(e + 1.f);
}

#define MFMA_F16 __builtin_amdgcn_mfma_f32_16x16x32_f16

// Poll-stage region kq (cols kq*256..+255), rows r0..r0+7 of this group's
// h slice into swizzled LDS. Gate: spin on 16 producer flags (one 64B line,
// one dword per lane) until all >= need, with s_sleep backoff. Then the
// r7 tagged data poll (usually one round). sc0|sc1 = fabric-coherent.
__device__ __forceinline__ void stage_quarter(const short* __restrict__ hsrc,
                                              short* __restrict__ htile,
                                              int row0, int cg, int kq,
                                              int lane, unsigned tag,
                                              const int* __restrict__ qflag,
                                              int need) {
    // ---- flag gate (cheap rounds: 64B/wave) ----
    {
        int fv, spin = 0;
        for (;;) {
            asm volatile("global_load_dword %0, %1, off sc0 sc1"
                         : "=&v"(fv) : "v"(qflag) : "memory");
            asm volatile("s_waitcnt vmcnt(0)" ::: "memory");
            if (__all(fv >= need)) break;
            __builtin_amdgcn_s_sleep(1);
            if (++spin > (1 << 20)) break;   // hang insurance only
        }
    }
    // ---- tagged data poll (self-validating; flag is only a hint) ----
    const int half = lane >> 5, gl = lane & 31, r0 = cg * 8;
    const short* a0 = hsrc + (size_t)(row0 + r0 + 0 + half) * Hn + kq * 256 + gl * 8;
    const short* a1 = hsrc + (size_t)(row0 + r0 + 2 + half) * Hn + kq * 256 + gl * 8;
    const short* a2 = hsrc + (size_t)(row0 + r0 + 4 + half) * Hn + kq * 256 + gl * 8;
    const short* a3 = hsrc + (size_t)(row0 + r0 + 6 + half) * Hn + kq * 256 + gl * 8;
    i32x4 t0, t1, t2, t3;
    int spin = 0;
    for (;;) {
        asm volatile("global_load_dwordx4 %0, %1, off sc0 sc1"
                     : "=&v"(t0) : "v"(a0) : "memory");
        asm volatile("global_load_dwordx4 %0, %1, off sc0 sc1"
                     : "=&v"(t1) : "v"(a1) : "memory");
        asm volatile("global_load_dwordx4 %0, %1, off sc0 sc1"
                     : "=&v"(t2) : "v"(a2) : "memory");
        asm volatile("global_load_dwordx4 %0, %1, off sc0 sc1"
                     : "=&v"(t3) : "v"(a3) : "memory");
        asm volatile("s_waitcnt vmcnt(0)" ::: "memory");
        unsigned bad = 0;
#pragma unroll
        for (int e = 0; e < 4; ++e)
            bad |= (unsigned)(t0[e] ^ tag) | (unsigned)(t1[e] ^ tag) |
                   (unsigned)(t2[e] ^ tag) | (unsigned)(t3[e] ^ tag);
        if (!__any(bad & 1u)) break;
        if (++spin > (1 << 20)) break;   // hang insurance only
    }
    i32x4 tv[4] = {t0, t1, t2, t3};
#pragma unroll
    for (int p = 0; p < 4; ++p) {
        int row = r0 + 2 * p + half;
        int g   = kq * 32 + gl;
        int idx = row * 128 + (g ^ (row & 7));
        *(i32x4*)(htile + idx * 8) = tv[p];
    }
}

__global__ __launch_bounds__(512, 2) void rnn_kernel(
    const float* __restrict__ x,      // [B][T]
    const float* __restrict__ W_ih,   // [1+H][H]
    const float* __restrict__ b_ih,   // [H]
    const float* __restrict__ W_ho,   // [H][O]
    const float* __restrict__ b_ho,   // [O]
    float* __restrict__ out,          // [B][O]
    short* __restrict__ hbuf,         // ws: 2 * B * H fp16
    int* __restrict__ flags)          // ws: [16 grp][8 mem][8 wave] (zeroed)
{
    const int tid  = threadIdx.x;
    const int lane = tid & 63;
    const int w    = tid >> 6;      // wave 0..7
    const int cg   = w >> 2;        // col-group 0..1 (64 cols each)
    const int kq   = w & 3;         // k-quarter 0..3; owns m-tile kq of its cg
    const int q    = lane >> 4;
    const int n    = lane & 15;     // batch row (B/D col)

    const int i = blockIdx.x & 15;  // batch group
    const int j = blockIdx.x >> 4;  // member 0..7
    const int colbase = j * 128 + cg * 64;
    const int owncol  = colbase + kq * 16 + 4 * q;  // owner lane's 4 h cols
    const int row0    = i * 16;

    // Flag addressing: consumer wave kq needs members 2kq,2kq+1, all 8
    // waves each -> 16 contiguous ints = one 64B line. One per lane&15.
    const int* qflag = flags + (i * 8 + 2 * kq) * 8 + (lane & 15);
    int*       fdst  = flags + (i * 8 + j) * 8 + w;   // this wave's flag

    __shared__ float x_lds[16][Tn + 1];     // 32.8 KB
    __shared__ short htile[16 * Hn];        // 32 KB swizzled fp16 h slice
    __shared__ float redbuf[2][8 * 3 * 256];// 48 KB b128 partial exchange
    __shared__ int   pairflag[4];           // region-pair arrival counters

    if (tid < 4) pairflag[tid] = 0;

    // Stage x rows (coalesced fp32).
    for (int idx = tid; idx < 16 * Tn; idx += 512) {
        int r = idx >> 9, tt = idx & (Tn - 1);
        x_lds[r][tt] = x[(row0 + r) * Tn + tt];
    }

    // A = W^T frags (fp16): wave (cg,kq), tile mt: lane (q,n) holds
    // A[m=n][k=kq*256+ks*32+q*8+e] = W_ih[1+k][colbase+mt*16+n].
    f16x8 wfrag[32];
#pragma unroll
    for (int mt = 0; mt < 4; ++mt)
#pragma unroll
        for (int ks = 0; ks < 8; ++ks) {
#pragma unroll
            for (int e = 0; e < 8; ++e) {
                int k = kq * 256 + ks * 32 + q * 8 + e;
                wfrag[mt * 8 + ks][e] =
                    (_Float16)W_ih[(size_t)(1 + k) * Hn + colbase + mt * 16 + n];
            }
        }
    const float4 bias4 = *(const float4*)(b_ih + owncol);
    const float4 w04   = *(const float4*)(W_ih + owncol);  // row 0 (x weight)

    __syncthreads();

    short* h0 = hbuf;
    short* h1 = hbuf + Bsz * Hn;
    const int swn   = n & 7;
    const int gbase = kq * 32;
    const int slot  = (q * 16 + n) * 4;   // lane's 16B slot in a redbuf plane
    const f32x4 zero4 = {0.f, 0.f, 0.f, 0.f};

    for (int t = 0; t < Tn; ++t) {
        const float xv = x_lds[n][t];
        f32x4 aown = {bias4.x + xv * w04.x, bias4.y + xv * w04.y,
                      bias4.z + xv * w04.z, bias4.w + xv * w04.w};
        f32x4 hv;

        if (t > 0) {
            // Flag-gated poll + stage of region kq only.
            stage_quarter((t & 1) ? h1 : h0, htile, row0, cg, kq, lane,
                          (unsigned)((t + 1) >> 1) & 1u, qflag, t);
            // Pairwise sync with region partner (other cg, same kq).
            asm volatile("s_waitcnt lgkmcnt(0)" ::: "memory");
            if (lane == 0)
                __hip_atomic_fetch_add(&pairflag[kq], 1, __ATOMIC_RELAXED,
                                       __HIP_MEMORY_SCOPE_WORKGROUP);
            while (__hip_atomic_load(&pairflag[kq], __ATOMIC_RELAXED,
                                     __HIP_MEMORY_SCOPE_WORKGROUP) < 2 * t) {}
            asm volatile("" ::: "memory");

            f32x4 acc0 = (kq == 0) ? aown : zero4;
            f32x4 acc1 = (kq == 1) ? aown : zero4;
            f32x4 acc2 = (kq == 2) ? aown : zero4;
            f32x4 acc3 = (kq == 3) ? aown : zero4;
            const i32x4* lrow = (const i32x4*)(htile + n * Hn);
#pragma unroll
            for (int ks = 0; ks < 8; ++ks) {
                f16x8 b = as_f16x8(lrow[(gbase + ks * 4 + q) ^ swn]);
                acc0 = MFMA_F16(wfrag[0 * 8 + ks], b, acc0, 0, 0, 0);
                acc1 = MFMA_F16(wfrag[1 * 8 + ks], b, acc1, 0, 0, 0);
                acc2 = MFMA_F16(wfrag[2 * 8 + ks], b, acc2, 0, 0, 0);
                acc3 = MFMA_F16(wfrag[3 * 8 + ks], b, acc3, 0, 0, 0);
            }

            // Exchange k-partials, b128 conflict-free, double-buffered.
            float* rb = redbuf[t & 1];
#define WRITE_PART(MT, ACC)                                                  \
            if (kq != MT) {                                                  \
                int src = (kq < MT) ? kq : kq - 1;                           \
                *(f32x4*)(rb + ((cg * 4 + MT) * 3 + src) * 256 + slot) = ACC;\
            }
            WRITE_PART(0, acc0)
            WRITE_PART(1, acc1)
            WRITE_PART(2, acc2)
            WRITE_PART(3, acc3)
#undef WRITE_PART
            __syncthreads();

            hv = (kq == 0) ? acc0 : (kq == 1) ? acc1 : (kq == 2) ? acc2 : acc3;
            const float* bp = rb + (cg * 4 + kq) * 3 * 256 + slot;
            f32x4 p0 = *(const f32x4*)(bp);
            f32x4 p1 = *(const f32x4*)(bp + 256);
            f32x4 p2 = *(const f32x4*)(bp + 512);
            hv = hv + p0 + p1 + p2;
        } else {
            hv = aown;
        }

        // Store h_{t+1}: buffer (t+1)&1, tag(t+1)=((t+2)>>1)&1 in bit 0 of
        // every dword. Fire-and-forget write-through; then fire-and-forget
        // flag t+1 (hint only — tags validate, so no ack wait needed).
        unsigned tagn = (unsigned)((t + 2) >> 1) & 1u;
        unsigned e0 = f2h(fast_tanh(hv[0])), e1 = f2h(fast_tanh(hv[1]));
        unsigned e2 = f2h(fast_tanh(hv[2])), e3 = f2h(fast_tanh(hv[3]));
        i32x2 pk;
        pk[0] = (int)(((e0 & ~1u) | tagn) | (e1 << 16));
        pk[1] = (int)(((e2 & ~1u) | tagn) | (e3 << 16));
        short* hdst = (((t + 1) & 1) ? h1 : h0) + (size_t)(row0 + n) * Hn + owncol;
        asm volatile("global_store_dwordx2 %0, %1, off sc0 sc1"
                     :: "v"(hdst), "v"(pk) : "memory");
        if (lane == 0) {
            int fval = t + 1;
            asm volatile("global_store_dword %0, %1, off sc0 sc1"
                         :: "v"(fdst), "v"(fval) : "memory");
        }
    }

    // ---- Epilogue: out[16i..+16][32j..+32] = h_T @ W_ho + b_ho ----
    // h_512 in buffer 0, tag 0, flags >= 512.
    stage_quarter(h0, htile, row0, cg, kq, lane, 0u, qflag, Tn);
    __syncthreads();

    f32x4 e0 = zero4, e1 = zero4;        // nt = 0,1 (16 out-cols each)
    {
        const i32x4* lrow = (const i32x4*)(htile + n * Hn);
#pragma unroll
        for (int kk = 0; kk < 4; ++kk) {
            f16x8 af = as_f16x8(lrow[(w * 16 + kk * 4 + q) ^ swn]);
            f16x8 b0, b1;
#pragma unroll
            for (int e = 0; e < 8; ++e) {
                const float* wp = W_ho +
                    (size_t)(w * 128 + kk * 32 + q * 8 + e) * On + j * 32 + n;
                b0[e] = (_Float16)wp[0];
                b1[e] = (_Float16)wp[16];
            }
            e0 = MFMA_F16(af, b0, e0, 0, 0, 0);
            e1 = MFMA_F16(af, b1, e1, 0, 0, 0);
        }
    }
    {   // scratch in redbuf[0]: [w][16 rows][33]: D[m=4q+r][col=nt*16+n].
        float* re = redbuf[0] + w * 528;
#pragma unroll
        for (int r = 0; r < 4; ++r) {
            re[(4 * q + r) * 33 + n]      = e0[r];
            re[(4 * q + r) * 33 + 16 + n] = e1[r];
        }
    }
    __syncthreads();
    {
        int r = tid >> 5, c = tid & 31;
        float s = b_ho[j * 32 + c];
#pragma unroll
        for (int w8 = 0; w8 < 8; ++w8)
            s += redbuf[0][w8 * 528 + r * 33 + c];
        out[(size_t)(row0 + r) * On + j * 32 + c] = s;
    }
}

extern "C" void kernel_launch(void* const* d_in, const int* in_sizes, int n_in,
                              void* d_out, int out_size, void* d_ws, size_t ws_size,
                              hipStream_t stream) {
    const float* x    = (const float*)d_in[0];
    const float* W_ih = (const float*)d_in[1];
    const float* b_ih = (const float*)d_in[2];
    const float* W_ho = (const float*)d_in[3];
    const float* b_ho = (const float*)d_in[4];
    float* out = (float*)d_out;

    size_t hbytes = (size_t)2 * Bsz * Hn * sizeof(short);
    size_t fbytes = (size_t)16 * 8 * 8 * sizeof(int);   // 4 KB flags
    if (ws_size < hbytes + fbytes) return;

    short* hbuf  = (short*)d_ws;
    int*   flags = (int*)((char*)d_ws + hbytes);

    // Flags are monotonic within a run; zero them per launch
    // (stream-ordered, graph-capture legal).
    hipMemsetAsync(flags, 0, fbytes, stream);

    rnn_kernel<<<128, 512, 0, stream>>>(x, W_ih, b_ih, W_ho, b_ho, out,
                                        hbuf, flags);
}

// Round 4
// 1233.986 us; speedup vs baseline: 3.6541x; 1.1655x over previous
//
#include <hip/hip_runtime.h>
#include <hip/hip_bf16.h>

// Elman RNN: B=256, T=512, H=1024, O=256 (fp32 in/out), MI355X gfx950.
// Round 11: canary polling (congestion relief with no added serial RT).
// Evidence ladder: r9 (2x poll BW, uncoalesced) = 4509us; r7 (4MB/round
// ~= 12 TB/s fabric polling) = 1080us; r10 (flag gate, +1 serial RT) =
// 1438us. Conclusion: exchange is fabric-CONGESTION-limited; fixes must
// cut poll bandwidth without adding a serial round trip. r11 keeps r7's
// structure verbatim but polls only the FIRST staging load (1KB/wave
// "canary"; its lanes carry both source members' tags) with s_sleep
// backoff, then issues the remaining 3 loads once, tag-validated with
// retry. Failed rounds now cost 8KB/block instead of 32KB -> ~4x less
// poll traffic; success path has the same 2-RT cost as r7.

#define Bsz 256
#define Tn  512
#define Hn  1024
#define On  256

typedef __attribute__((ext_vector_type(8))) _Float16 f16x8;  // 4 VGPR
typedef __attribute__((ext_vector_type(4))) float f32x4;
typedef __attribute__((ext_vector_type(4))) int   i32x4;
typedef __attribute__((ext_vector_type(2))) int   i32x2;

__device__ __forceinline__ unsigned f2h(float f) {
    _Float16 h = (_Float16)f;
    union { _Float16 h; unsigned short s; } u; u.h = h;
    return (unsigned)u.s;
}

__device__ __forceinline__ f16x8 as_f16x8(i32x4 v) {
    union { i32x4 i; f16x8 h; } u; u.i = v; return u.h;
}

// tanh = (e^{2x}-1)/(e^{2x}+1); |err| ~1e-6 << fp16 rounding.
__device__ __forceinline__ float fast_tanh(float x) {
    float xc = fminf(fmaxf(x, -9.f), 9.f);
    float e  = __builtin_amdgcn_exp2f(xc * 2.8853900817779268f);
    return (e - 1.f) * __builtin_amdgcn_rcpf(e + 1.f);
}

#define MFMA_F16 __builtin_amdgcn_mfma_f32_16x16x32_f16

// Poll-stage region kq (cols kq*256..+255), rows r0..r0+7 of this group's
// h slice into swizzled LDS. Canary scheme: spin on load a0 only (rows
// r0,r0+1 — lanes gl<16 carry member 2kq's tags, gl>=16 member 2kq+1's),
// s_sleep(1) between failed rounds. Then issue a1..a3 once and validate
// (same producer store instructions; lines rarely lag). sc0|sc1 =
// fabric-coherent on both sides (r7-proven).
__device__ __forceinline__ void stage_quarter(const short* __restrict__ hsrc,
                                              short* __restrict__ htile,
                                              int row0, int cg, int kq,
                                              int lane, unsigned tag) {
    const int half = lane >> 5, gl = lane & 31, r0 = cg * 8;
    const short* a0 = hsrc + (size_t)(row0 + r0 + 0 + half) * Hn + kq * 256 + gl * 8;
    const short* a1 = hsrc + (size_t)(row0 + r0 + 2 + half) * Hn + kq * 256 + gl * 8;
    const short* a2 = hsrc + (size_t)(row0 + r0 + 4 + half) * Hn + kq * 256 + gl * 8;
    const short* a3 = hsrc + (size_t)(row0 + r0 + 6 + half) * Hn + kq * 256 + gl * 8;
    i32x4 t0, t1, t2, t3;
    int spin = 0;
    // ---- canary: 1KB/wave rounds until rows r0,r0+1 are fresh ----
    for (;;) {
        asm volatile("global_load_dwordx4 %0, %1, off sc0 sc1"
                     : "=&v"(t0) : "v"(a0) : "memory");
        asm volatile("s_waitcnt vmcnt(0)" ::: "memory");
        unsigned bad = 0;
#pragma unroll
        for (int e = 0; e < 4; ++e) bad |= (unsigned)t0[e] ^ tag;
        if (!__any(bad & 1u)) break;
        __builtin_amdgcn_s_sleep(1);
        if (++spin > (1 << 20)) break;   // hang insurance only
    }
    // ---- bulk: remaining 3 loads, validated, retried (rare) ----
    for (;;) {
        asm volatile("global_load_dwordx4 %0, %1, off sc0 sc1"
                     : "=&v"(t1) : "v"(a1) : "memory");
        asm volatile("global_load_dwordx4 %0, %1, off sc0 sc1"
                     : "=&v"(t2) : "v"(a2) : "memory");
        asm volatile("global_load_dwordx4 %0, %1, off sc0 sc1"
                     : "=&v"(t3) : "v"(a3) : "memory");
        asm volatile("s_waitcnt vmcnt(0)" ::: "memory");
        unsigned bad = 0;
#pragma unroll
        for (int e = 0; e < 4; ++e)
            bad |= (unsigned)(t1[e] ^ tag) | (unsigned)(t2[e] ^ tag) |
                   (unsigned)(t3[e] ^ tag);
        if (!__any(bad & 1u)) break;
        if (++spin > (1 << 20)) break;   // hang insurance only
    }
    i32x4 tv[4] = {t0, t1, t2, t3};
#pragma unroll
    for (int p = 0; p < 4; ++p) {
        int row = r0 + 2 * p + half;
        int g   = kq * 32 + gl;
        int idx = row * 128 + (g ^ (row & 7));
        *(i32x4*)(htile + idx * 8) = tv[p];
    }
}

__global__ __launch_bounds__(512, 2) void rnn_kernel(
    const float* __restrict__ x,      // [B][T]
    const float* __restrict__ W_ih,   // [1+H][H]
    const float* __restrict__ b_ih,   // [H]
    const float* __restrict__ W_ho,   // [H][O]
    const float* __restrict__ b_ho,   // [O]
    float* __restrict__ out,          // [B][O]
    short* __restrict__ hbuf)         // ws: 2 * B * H fp16
{
    const int tid  = threadIdx.x;
    const int lane = tid & 63;
    const int w    = tid >> 6;      // wave 0..7
    const int cg   = w >> 2;        // col-group 0..1 (64 cols each)
    const int kq   = w & 3;         // k-quarter 0..3; owns m-tile kq of its cg
    const int q    = lane >> 4;     // 0..3
    const int n    = lane & 15;     // batch row (B/D col)

    const int i = blockIdx.x & 15;  // batch group
    const int j = blockIdx.x >> 4;  // member 0..7
    const int colbase = j * 128 + cg * 64;
    const int owncol  = colbase + kq * 16 + 4 * q;  // owner lane's 4 h cols
    const int row0    = i * 16;

    __shared__ float x_lds[16][Tn + 1];     // 32.8 KB
    __shared__ short htile[16 * Hn];        // 32 KB swizzled fp16 h slice
    __shared__ float redbuf[2][8 * 3 * 256];// 48 KB b128 partial exchange
    __shared__ int   pairflag[4];           // region-pair arrival counters

    if (tid < 4) pairflag[tid] = 0;

    // Stage x rows (coalesced fp32).
    for (int idx = tid; idx < 16 * Tn; idx += 512) {
        int r = idx >> 9, tt = idx & (Tn - 1);
        x_lds[r][tt] = x[(row0 + r) * Tn + tt];
    }

    // A = W^T frags (fp16): wave (cg,kq), tile mt: lane (q,n) holds
    // A[m=n][k=kq*256+ks*32+q*8+e] = W_ih[1+k][colbase+mt*16+n].
    f16x8 wfrag[32];
#pragma unroll
    for (int mt = 0; mt < 4; ++mt)
#pragma unroll
        for (int ks = 0; ks < 8; ++ks) {
#pragma unroll
            for (int e = 0; e < 8; ++e) {
                int k = kq * 256 + ks * 32 + q * 8 + e;
                wfrag[mt * 8 + ks][e] =
                    (_Float16)W_ih[(size_t)(1 + k) * Hn + colbase + mt * 16 + n];
            }
        }
    const float4 bias4 = *(const float4*)(b_ih + owncol);
    const float4 w04   = *(const float4*)(W_ih + owncol);  // row 0 (x weight)

    __syncthreads();

    short* h0 = hbuf;
    short* h1 = hbuf + Bsz * Hn;
    const int swn   = n & 7;
    const int gbase = kq * 32;
    const int slot  = (q * 16 + n) * 4;   // lane's 16B slot in a redbuf plane
    const f32x4 zero4 = {0.f, 0.f, 0.f, 0.f};

    for (int t = 0; t < Tn; ++t) {
        const float xv = x_lds[n][t];
        f32x4 aown = {bias4.x + xv * w04.x, bias4.y + xv * w04.y,
                      bias4.z + xv * w04.z, bias4.w + xv * w04.w};
        f32x4 hv;

        if (t > 0) {
            // Canary-gated poll + stage of region kq only.
            stage_quarter((t & 1) ? h1 : h0, htile, row0, cg, kq, lane,
                          (unsigned)((t + 1) >> 1) & 1u);
            // Pairwise sync with region partner (other cg, same kq).
            asm volatile("s_waitcnt lgkmcnt(0)" ::: "memory");
            if (lane == 0)
                __hip_atomic_fetch_add(&pairflag[kq], 1, __ATOMIC_RELAXED,
                                       __HIP_MEMORY_SCOPE_WORKGROUP);
            while (__hip_atomic_load(&pairflag[kq], __ATOMIC_RELAXED,
                                     __HIP_MEMORY_SCOPE_WORKGROUP) < 2 * t) {}
            asm volatile("" ::: "memory");

            f32x4 acc0 = (kq == 0) ? aown : zero4;
            f32x4 acc1 = (kq == 1) ? aown : zero4;
            f32x4 acc2 = (kq == 2) ? aown : zero4;
            f32x4 acc3 = (kq == 3) ? aown : zero4;
            const i32x4* lrow = (const i32x4*)(htile + n * Hn);
#pragma unroll
            for (int ks = 0; ks < 8; ++ks) {
                f16x8 b = as_f16x8(lrow[(gbase + ks * 4 + q) ^ swn]);
                acc0 = MFMA_F16(wfrag[0 * 8 + ks], b, acc0, 0, 0, 0);
                acc1 = MFMA_F16(wfrag[1 * 8 + ks], b, acc1, 0, 0, 0);
                acc2 = MFMA_F16(wfrag[2 * 8 + ks], b, acc2, 0, 0, 0);
                acc3 = MFMA_F16(wfrag[3 * 8 + ks], b, acc3, 0, 0, 0);
            }

            // Exchange k-partials, b128 conflict-free, double-buffered.
            float* rb = redbuf[t & 1];
#define WRITE_PART(MT, ACC)                                                  \
            if (kq != MT) {                                                  \
                int src = (kq < MT) ? kq : kq - 1;                           \
                *(f32x4*)(rb + ((cg * 4 + MT) * 3 + src) * 256 + slot) = ACC;\
            }
            WRITE_PART(0, acc0)
            WRITE_PART(1, acc1)
            WRITE_PART(2, acc2)
            WRITE_PART(3, acc3)
#undef WRITE_PART
            __syncthreads();

            hv = (kq == 0) ? acc0 : (kq == 1) ? acc1 : (kq == 2) ? acc2 : acc3;
            const float* bp = rb + (cg * 4 + kq) * 3 * 256 + slot;
            f32x4 p0 = *(const f32x4*)(bp);
            f32x4 p1 = *(const f32x4*)(bp + 256);
            f32x4 p2 = *(const f32x4*)(bp + 512);
            hv = hv + p0 + p1 + p2;
        } else {
            hv = aown;
        }

        // Store h_{t+1}: buffer (t+1)&1, tag(t+1)=((t+2)>>1)&1 in bit 0 of
        // every dword. Fire-and-forget write-through (proven visibility).
        unsigned tagn = (unsigned)((t + 2) >> 1) & 1u;
        unsigned e0 = f2h(fast_tanh(hv[0])), e1 = f2h(fast_tanh(hv[1]));
        unsigned e2 = f2h(fast_tanh(hv[2])), e3 = f2h(fast_tanh(hv[3]));
        i32x2 pk;
        pk[0] = (int)(((e0 & ~1u) | tagn) | (e1 << 16));
        pk[1] = (int)(((e2 & ~1u) | tagn) | (e3 << 16));
        short* hdst = (((t + 1) & 1) ? h1 : h0) + (size_t)(row0 + n) * Hn + owncol;
        asm volatile("global_store_dwordx2 %0, %1, off sc0 sc1"
                     :: "v"(hdst), "v"(pk) : "memory");
    }

    // ---- Epilogue: out[16i..+16][32j..+32] = h_T @ W_ho + b_ho ----
    // h_512 in buffer 0, tag 0. All quarters staged, then full barrier.
    stage_quarter(h0, htile, row0, cg, kq, lane, 0u);
    __syncthreads();

    f32x4 e0 = zero4, e1 = zero4;        // nt = 0,1 (16 out-cols each)
    {
        const i32x4* lrow = (const i32x4*)(htile + n * Hn);
#pragma unroll
        for (int kk = 0; kk < 4; ++kk) {
            f16x8 af = as_f16x8(lrow[(w * 16 + kk * 4 + q) ^ swn]);
            f16x8 b0, b1;
#pragma unroll
            for (int e = 0; e < 8; ++e) {
                const float* wp = W_ho +
                    (size_t)(w * 128 + kk * 32 + q * 8 + e) * On + j * 32 + n;
                b0[e] = (_Float16)wp[0];
                b1[e] = (_Float16)wp[16];
            }
            e0 = MFMA_F16(af, b0, e0, 0, 0, 0);
            e1 = MFMA_F16(af, b1, e1, 0, 0, 0);
        }
    }
    {   // scratch in redbuf[0]: [w][16 rows][33]: D[m=4q+r][col=nt*16+n].
        float* re = redbuf[0] + w * 528;
#pragma unroll
        for (int r = 0; r < 4; ++r) {
            re[(4 * q + r) * 33 + n]      = e0[r];
            re[(4 * q + r) * 33 + 16 + n] = e1[r];
        }
    }
    __syncthreads();
    {
        int r = tid >> 5, c = tid & 31;
        float s = b_ho[j * 32 + c];
#pragma unroll
        for (int w8 = 0; w8 < 8; ++w8)
            s += redbuf[0][w8 * 528 + r * 33 + c];
        out[(size_t)(row0 + r) * On + j * 32 + c] = s;
    }
}

extern "C" void kernel_launch(void* const* d_in, const int* in_sizes, int n_in,
                              void* d_out, int out_size, void* d_ws, size_t ws_size,
                              hipStream_t stream) {
    const float* x    = (const float*)d_in[0];
    const float* W_ih = (const float*)d_in[1];
    const float* b_ih = (const float*)d_in[2];
    const float* W_ho = (const float*)d_in[3];
    const float* b_ho = (const float*)d_in[4];
    float* out = (float*)d_out;

    size_t need = (size_t)2 * Bsz * Hn * sizeof(short);
    if (ws_size < need) return;

    short* hbuf = (short*)d_ws;

    rnn_kernel<<<128, 512, 0, stream>>>(x, W_ih, b_ih, W_ho, b_ho, out, hbuf);
}

// Round 5
// 1092.133 us; speedup vs baseline: 4.1287x; 1.1299x over previous
//
#include <hip/hip_runtime.h>
#include <hip/hip_bf16.h>

// Elman RNN: B=256, T=512, H=1024, O=256 (fp32 in/out), MI355X gfx950.
// Round 12: r7 structure + store-drain waitcnt (priority-inversion fix).
// Evidence ladder: r7 (poll-all, no serialization) = 1080us; r10 (flag
// gate, +1 serial RT) = 1438us; r11 (canary, +1 serial bulk RT, 4x less
// poll traffic) = 1234us. r11's traffic cut bought nothing -> polling
// congestion is NOT dominant; the exchange cost is store-VISIBILITY +
// detect. r7's h-store is fire-and-forget and the wave immediately floods
// the pipe with poll loads (each with a vmcnt(0) waiter); the un-waited
// store can linger behind them, delaying the very visibility all peers
// poll for. r12 adds exactly one instruction vs r7: s_waitcnt vmcnt(0)
// after the h-store, before the next poll round. Everything else is r7
// verbatim (quarter-granular arrival, pairflag, redbuf, tag-in-bit0).

#define Bsz 256
#define Tn  512
#define Hn  1024
#define On  256

typedef __attribute__((ext_vector_type(8))) _Float16 f16x8;  // 4 VGPR
typedef __attribute__((ext_vector_type(4))) float f32x4;
typedef __attribute__((ext_vector_type(4))) int   i32x4;
typedef __attribute__((ext_vector_type(2))) int   i32x2;

__device__ __forceinline__ unsigned f2h(float f) {
    _Float16 h = (_Float16)f;
    union { _Float16 h; unsigned short s; } u; u.h = h;
    return (unsigned)u.s;
}

__device__ __forceinline__ f16x8 as_f16x8(i32x4 v) {
    union { i32x4 i; f16x8 h; } u; u.i = v; return u.h;
}

// tanh = (e^{2x}-1)/(e^{2x}+1); |err| ~1e-6 << fp16 rounding.
__device__ __forceinline__ float fast_tanh(float x) {
    float xc = fminf(fmaxf(x, -9.f), 9.f);
    float e  = __builtin_amdgcn_exp2f(xc * 2.8853900817779268f);
    return (e - 1.f) * __builtin_amdgcn_rcpf(e + 1.f);
}

#define MFMA_F16 __builtin_amdgcn_mfma_f32_16x16x32_f16

// Poll-stage region kq (cols kq*256..+255), rows r0..r0+7 of this group's
// h slice into swizzled LDS. Each load instr: lanes 0-31 row r, lanes
// 32-63 row r+1, 512B contiguous per row (4 full lines each). All 4 loads
// in flight every round (no serialization); tags validate everything.
__device__ __forceinline__ void stage_quarter(const short* __restrict__ hsrc,
                                              short* __restrict__ htile,
                                              int row0, int cg, int kq,
                                              int lane, unsigned tag) {
    const int half = lane >> 5, gl = lane & 31, r0 = cg * 8;
    const short* a0 = hsrc + (size_t)(row0 + r0 + 0 + half) * Hn + kq * 256 + gl * 8;
    const short* a1 = hsrc + (size_t)(row0 + r0 + 2 + half) * Hn + kq * 256 + gl * 8;
    const short* a2 = hsrc + (size_t)(row0 + r0 + 4 + half) * Hn + kq * 256 + gl * 8;
    const short* a3 = hsrc + (size_t)(row0 + r0 + 6 + half) * Hn + kq * 256 + gl * 8;
    i32x4 t0, t1, t2, t3;
    int spin = 0;
    for (;;) {
        asm volatile("global_load_dwordx4 %0, %1, off sc0 sc1"
                     : "=&v"(t0) : "v"(a0) : "memory");
        asm volatile("global_load_dwordx4 %0, %1, off sc0 sc1"
                     : "=&v"(t1) : "v"(a1) : "memory");
        asm volatile("global_load_dwordx4 %0, %1, off sc0 sc1"
                     : "=&v"(t2) : "v"(a2) : "memory");
        asm volatile("global_load_dwordx4 %0, %1, off sc0 sc1"
                     : "=&v"(t3) : "v"(a3) : "memory");
        asm volatile("s_waitcnt vmcnt(0)" ::: "memory");
        unsigned bad = 0;
#pragma unroll
        for (int e = 0; e < 4; ++e)
            bad |= (unsigned)(t0[e] ^ tag) | (unsigned)(t1[e] ^ tag) |
                   (unsigned)(t2[e] ^ tag) | (unsigned)(t3[e] ^ tag);
        if (!__any(bad & 1u)) break;
        if (++spin > (1 << 20)) break;   // hang insurance only
    }
    i32x4 tv[4] = {t0, t1, t2, t3};
#pragma unroll
    for (int p = 0; p < 4; ++p) {
        int row = r0 + 2 * p + half;
        int g   = kq * 32 + gl;
        int idx = row * 128 + (g ^ (row & 7));
        *(i32x4*)(htile + idx * 8) = tv[p];
    }
}

__global__ __launch_bounds__(512, 2) void rnn_kernel(
    const float* __restrict__ x,      // [B][T]
    const float* __restrict__ W_ih,   // [1+H][H]
    const float* __restrict__ b_ih,   // [H]
    const float* __restrict__ W_ho,   // [H][O]
    const float* __restrict__ b_ho,   // [O]
    float* __restrict__ out,          // [B][O]
    short* __restrict__ hbuf)         // ws: 2 * B * H fp16
{
    const int tid  = threadIdx.x;
    const int lane = tid & 63;
    const int w    = tid >> 6;      // wave 0..7
    const int cg   = w >> 2;        // col-group 0..1 (64 cols each)
    const int kq   = w & 3;         // k-quarter 0..3; owns m-tile kq of its cg
    const int q    = lane >> 4;     // 0..3
    const int n    = lane & 15;     // batch row (B/D col)

    const int i = blockIdx.x & 15;  // batch group
    const int j = blockIdx.x >> 4;  // member 0..7
    const int colbase = j * 128 + cg * 64;
    const int owncol  = colbase + kq * 16 + 4 * q;  // owner lane's 4 h cols
    const int row0    = i * 16;

    __shared__ float x_lds[16][Tn + 1];     // 32.8 KB
    __shared__ short htile[16 * Hn];        // 32 KB swizzled fp16 h slice
    __shared__ float redbuf[2][8 * 3 * 256];// 48 KB b128 partial exchange
    __shared__ int   pairflag[4];           // region-pair arrival counters

    if (tid < 4) pairflag[tid] = 0;

    // Stage x rows (coalesced fp32).
    for (int idx = tid; idx < 16 * Tn; idx += 512) {
        int r = idx >> 9, tt = idx & (Tn - 1);
        x_lds[r][tt] = x[(row0 + r) * Tn + tt];
    }

    // A = W^T frags (fp16): wave (cg,kq), tile mt: lane (q,n) holds
    // A[m=n][k=kq*256+ks*32+q*8+e] = W_ih[1+k][colbase+mt*16+n].
    f16x8 wfrag[32];
#pragma unroll
    for (int mt = 0; mt < 4; ++mt)
#pragma unroll
        for (int ks = 0; ks < 8; ++ks) {
#pragma unroll
            for (int e = 0; e < 8; ++e) {
                int k = kq * 256 + ks * 32 + q * 8 + e;
                wfrag[mt * 8 + ks][e] =
                    (_Float16)W_ih[(size_t)(1 + k) * Hn + colbase + mt * 16 + n];
            }
        }
    const float4 bias4 = *(const float4*)(b_ih + owncol);
    const float4 w04   = *(const float4*)(W_ih + owncol);  // row 0 (x weight)

    __syncthreads();

    short* h0 = hbuf;
    short* h1 = hbuf + Bsz * Hn;
    const int swn   = n & 7;
    const int gbase = kq * 32;
    const int slot  = (q * 16 + n) * 4;   // lane's 16B slot in a redbuf plane
    const f32x4 zero4 = {0.f, 0.f, 0.f, 0.f};

    for (int t = 0; t < Tn; ++t) {
        const float xv = x_lds[n][t];
        f32x4 aown = {bias4.x + xv * w04.x, bias4.y + xv * w04.y,
                      bias4.z + xv * w04.z, bias4.w + xv * w04.w};
        f32x4 hv;

        if (t > 0) {
            // Poll + stage ONLY region kq (our 2 source members).
            stage_quarter((t & 1) ? h1 : h0, htile, row0, cg, kq, lane,
                          (unsigned)((t + 1) >> 1) & 1u);
            // Pairwise sync with region partner (other cg, same kq).
            asm volatile("s_waitcnt lgkmcnt(0)" ::: "memory");
            if (lane == 0)
                __hip_atomic_fetch_add(&pairflag[kq], 1, __ATOMIC_RELAXED,
                                       __HIP_MEMORY_SCOPE_WORKGROUP);
            while (__hip_atomic_load(&pairflag[kq], __ATOMIC_RELAXED,
                                     __HIP_MEMORY_SCOPE_WORKGROUP) < 2 * t) {}
            asm volatile("" ::: "memory");

            f32x4 acc0 = (kq == 0) ? aown : zero4;
            f32x4 acc1 = (kq == 1) ? aown : zero4;
            f32x4 acc2 = (kq == 2) ? aown : zero4;
            f32x4 acc3 = (kq == 3) ? aown : zero4;
            const i32x4* lrow = (const i32x4*)(htile + n * Hn);
#pragma unroll
            for (int ks = 0; ks < 8; ++ks) {
                f16x8 b = as_f16x8(lrow[(gbase + ks * 4 + q) ^ swn]);
                acc0 = MFMA_F16(wfrag[0 * 8 + ks], b, acc0, 0, 0, 0);
                acc1 = MFMA_F16(wfrag[1 * 8 + ks], b, acc1, 0, 0, 0);
                acc2 = MFMA_F16(wfrag[2 * 8 + ks], b, acc2, 0, 0, 0);
                acc3 = MFMA_F16(wfrag[3 * 8 + ks], b, acc3, 0, 0, 0);
            }

            // Exchange k-partials, b128 conflict-free, double-buffered.
            float* rb = redbuf[t & 1];
#define WRITE_PART(MT, ACC)                                                  \
            if (kq != MT) {                                                  \
                int src = (kq < MT) ? kq : kq - 1;                           \
                *(f32x4*)(rb + ((cg * 4 + MT) * 3 + src) * 256 + slot) = ACC;\
            }
            WRITE_PART(0, acc0)
            WRITE_PART(1, acc1)
            WRITE_PART(2, acc2)
            WRITE_PART(3, acc3)
#undef WRITE_PART
            __syncthreads();

            hv = (kq == 0) ? acc0 : (kq == 1) ? acc1 : (kq == 2) ? acc2 : acc3;
            const float* bp = rb + (cg * 4 + kq) * 3 * 256 + slot;
            f32x4 p0 = *(const f32x4*)(bp);
            f32x4 p1 = *(const f32x4*)(bp + 256);
            f32x4 p2 = *(const f32x4*)(bp + 512);
            hv = hv + p0 + p1 + p2;
        } else {
            hv = aown;
        }

        // Store h_{t+1}: buffer (t+1)&1, tag(t+1)=((t+2)>>1)&1 in bit 0 of
        // every dword. Write-through, then DRAIN (s_waitcnt vmcnt(0)) so
        // the store reaches the coherence point before this wave floods
        // the pipe with next-step poll loads. The drain is the r12 change:
        // our store is on our PEERS' critical path; polls have slack.
        unsigned tagn = (unsigned)((t + 2) >> 1) & 1u;
        unsigned e0 = f2h(fast_tanh(hv[0])), e1 = f2h(fast_tanh(hv[1]));
        unsigned e2 = f2h(fast_tanh(hv[2])), e3 = f2h(fast_tanh(hv[3]));
        i32x2 pk;
        pk[0] = (int)(((e0 & ~1u) | tagn) | (e1 << 16));
        pk[1] = (int)(((e2 & ~1u) | tagn) | (e3 << 16));
        short* hdst = (((t + 1) & 1) ? h1 : h0) + (size_t)(row0 + n) * Hn + owncol;
        asm volatile("global_store_dwordx2 %0, %1, off sc0 sc1"
                     :: "v"(hdst), "v"(pk) : "memory");
        asm volatile("s_waitcnt vmcnt(0)" ::: "memory");
    }

    // ---- Epilogue: out[16i..+16][32j..+32] = h_T @ W_ho + b_ho ----
    // h_512 in buffer 0, tag 0. All quarters staged, then full barrier.
    stage_quarter(h0, htile, row0, cg, kq, lane, 0u);
    __syncthreads();

    f32x4 e0 = zero4, e1 = zero4;        // nt = 0,1 (16 out-cols each)
    {
        const i32x4* lrow = (const i32x4*)(htile + n * Hn);
#pragma unroll
        for (int kk = 0; kk < 4; ++kk) {
            f16x8 af = as_f16x8(lrow[(w * 16 + kk * 4 + q) ^ swn]);
            f16x8 b0, b1;
#pragma unroll
            for (int e = 0; e < 8; ++e) {
                const float* wp = W_ho +
                    (size_t)(w * 128 + kk * 32 + q * 8 + e) * On + j * 32 + n;
                b0[e] = (_Float16)wp[0];
                b1[e] = (_Float16)wp[16];
            }
            e0 = MFMA_F16(af, b0, e0, 0, 0, 0);
            e1 = MFMA_F16(af, b1, e1, 0, 0, 0);
        }
    }
    {   // scratch in redbuf[0]: [w][16 rows][33]: D[m=4q+r][col=nt*16+n].
        float* re = redbuf[0] + w * 528;
#pragma unroll
        for (int r = 0; r < 4; ++r) {
            re[(4 * q + r) * 33 + n]      = e0[r];
            re[(4 * q + r) * 33 + 16 + n] = e1[r];
        }
    }
    __syncthreads();
    {
        int r = tid >> 5, c = tid & 31;
        float s = b_ho[j * 32 + c];
#pragma unroll
        for (int w8 = 0; w8 < 8; ++w8)
            s += redbuf[0][w8 * 528 + r * 33 + c];
        out[(size_t)(row0 + r) * On + j * 32 + c] = s;
    }
}

extern "C" void kernel_launch(void* const* d_in, const int* in_sizes, int n_in,
                              void* d_out, int out_size, void* d_ws, size_t ws_size,
                              hipStream_t stream) {
    const float* x    = (const float*)d_in[0];
    const float* W_ih = (const float*)d_in[1];
    const float* b_ih = (const float*)d_in[2];
    const float* W_ho = (const float*)d_in[3];
    const float* b_ho = (const float*)d_in[4];
    float* out = (float*)d_out;

    size_t need = (size_t)2 * Bsz * Hn * sizeof(short);
    if (ws_size < need) return;

    short* hbuf = (short*)d_ws;

    rnn_kernel<<<128, 512, 0, stream>>>(x, W_ih, b_ih, W_ho, b_ho, out, hbuf);
}